// Round 6
// baseline (665.902 us; speedup 1.0000x reference)
//
#include <hip/hip_runtime.h>

#define NN 100000
#define NE 1600000
#define DD 128
#define CAP 64      // padded-CSR capacity (line-aligned rows); P(Poisson(16) >= 64) ~ 1e-19
#define NGROUP 256  // edge-slice groups for filtered scatter

// ---------- bf16 helpers (manual, RNE) ----------
static __device__ __forceinline__ unsigned short f2b(float f) {
  unsigned int x = __float_as_uint(f);
  unsigned int r = x + 0x7fffu + ((x >> 16) & 1u);
  return (unsigned short)(r >> 16);
}
static __device__ __forceinline__ float b2f(unsigned short u) {
  return __uint_as_float(((unsigned int)u) << 16);
}

typedef __attribute__((ext_vector_type(8))) short short8;
typedef __attribute__((ext_vector_type(4))) float f32x4;

union V8 {
  uint4 u4;
  short8 s8;
  unsigned short us[8];
};

// ---------- edge-index dtype detector ----------
__global__ void detect_k(const int* __restrict__ ei, int* __restrict__ flag) {
  int v = ei[2 * threadIdx.x + 1];
  unsigned long long b = __ballot(v != 0);
  if (threadIdx.x == 0) *flag = (b == 0ull) ? 1 : 0;
}

// ---------- fp32 -> bf16 cast (x input) ----------
__global__ __launch_bounds__(256) void cast_k(const float* __restrict__ x,
                                              unsigned short* __restrict__ x16) {
  size_t i = ((size_t)blockIdx.x * 256 + threadIdx.x) * 8;
  f32x4 a = *(const f32x4*)(x + i);
  f32x4 b = *(const f32x4*)(x + i + 4);
  V8 v;
#pragma unroll
  for (int j = 0; j < 4; ++j) {
    v.us[j] = f2b(a[j]);
    v.us[4 + j] = f2b(b[j]);
  }
  *(uint4*)(x16 + i) = v.u4;
}

// ---------- pack edges to (src,dst) int pairs + zero cnt ----------
__global__ __launch_bounds__(256) void pack_k(const int* __restrict__ ei,
                                              int* __restrict__ packed,  // [NE][2]
                                              int* __restrict__ cnt,
                                              const int* __restrict__ flag) {
  const int mode = *flag;
  const int gid = blockIdx.x * 256 + threadIdx.x;
  int s, d;
  if (mode) {  // int64 little-endian, values < 2^31: low word at even offset
    s = ei[2 * (size_t)gid];
    d = ei[2 * ((size_t)NE + gid)];
  } else {
    s = ei[gid];
    d = ei[NE + gid];
  }
  packed[2 * gid] = s;
  packed[2 * gid + 1] = d;
  if (gid < NN) cnt[gid] = 0;
}

// ---------- padded-CSR scatter, XCD-range-filtered ----------
// blockIdx&7 selects a dst range; same-range blocks land on the same XCD
// (blockIdx%8 round-robin) -> cnt/csr lines written by one XCD only.
// packed is read NON-TEMPORALLY (as long long) so the 12.8MB stream doesn't
// evict the dirty csr/cnt working set (~3.3MB/XCD) from L2 mid-pass.
__global__ __launch_bounds__(256) void scatter_k(const long long* __restrict__ packed,
                                                 int* __restrict__ cnt,
                                                 int* __restrict__ csr) {
  const int r = blockIdx.x & 7;
  const int g = blockIdx.x >> 3;
  const int lo = r * (NN / 8), hi = lo + (NN / 8);
  for (int e = g * 256 + threadIdx.x; e < NE; e += NGROUP * 256) {
    long long sd = __builtin_nontemporal_load(&packed[e]);
    const int s = (int)(sd & 0xffffffffll);
    const int d = (int)(sd >> 32);
    if (d >= lo && d < hi) {
      int c = atomicAdd(&cnt[d], 1);
      if (c < CAP) csr[(size_t)d * CAP + c] = s;
    }
  }
}

// ---------- weight prep: transpose+cast all 7 matrices to bf16 wT[n][k] ----------
// seg m (16384 shorts each): 0-2 = W1[l], 3-5 = W2[l], 6 = fW1, 7 = fW2 (64x128).
__global__ __launch_bounds__(256) void wprep_k(const float* __restrict__ W1,
                                               const float* __restrict__ W2,
                                               const float* __restrict__ fW1,
                                               const float* __restrict__ fW2,
                                               unsigned short* __restrict__ wt) {
  int b = blockIdx.x;
  const float* src;
  int moff, N;
  if (b < 192) {
    int m = b >> 6;
    src = W1 + m * 16384;
    moff = m * 16384;
    N = 128;
    b &= 63;
  } else if (b < 384) {
    int m = (b - 192) >> 6;
    src = W2 + m * 16384;
    moff = (3 + m) * 16384;
    N = 128;
    b = (b - 192) & 63;
  } else if (b < 448) {
    src = fW1;
    moff = 6 * 16384;
    N = 128;
    b -= 384;
  } else {
    src = fW2;
    moff = 7 * 16384;
    N = 64;
    b -= 448;
  }
  int idx = b * 256 + threadIdx.x;  // n*128 + k
  int n = idx >> 7, k = idx & 127;
  if (n < N) wt[moff + idx] = f2b(src[(size_t)k * N + n]);
}

// ---------- MFMA GEMM: C[M x NCOLS] = A[M x 128] @ wT^T + bias ----------
// wT is pre-transposed bf16 [NCOLS][128].
// AMODE: 1 = A bf16 plain, 2 = A bf16 + BN(scale,shift from raw stats)+ReLU,
//        3 = A = x16[row] + sum_{s in in(row)} x16[s]  (fused GIN gather)
// EPI:   0 = store bf16, 1 = relu + store bf16, 2 = store fp32
// STATS: 1 = accumulate per-column sum/sumsq of the (rounded) output into stats_out
template <int AMODE, int NCOLS, int EPI, int STATS>
__global__ __launch_bounds__(256) void gemm_k(const unsigned short* __restrict__ Aptr,
                                              const unsigned short* __restrict__ wT,
                                              const float* __restrict__ bias,
                                              const float* __restrict__ bn_stats,
                                              const float* __restrict__ gamma,
                                              const float* __restrict__ beta,
                                              void* __restrict__ Cptr,
                                              float* __restrict__ stats_out,
                                              const int* __restrict__ cnt,
                                              const int* __restrict__ csr) {
  __shared__ unsigned short bT[NCOLS][136];  // 16B-aligned rows, benign 2-way alias
  __shared__ float biasS[NCOLS];
  __shared__ float scS[128];
  __shared__ float shS[128];
  __shared__ float sS[NCOLS];
  __shared__ float s2S[NCOLS];
  const int tid = threadIdx.x;

  for (int i = tid; i < NCOLS * 16; i += 256) {
    int n = i >> 4, k8 = (i & 15) << 3;
    *(uint4*)&bT[n][k8] = *(const uint4*)(wT + n * 128 + k8);
  }
  if (tid < NCOLS) biasS[tid] = bias[tid];
  if (AMODE == 2 && tid < 128) {
    const float inv_n = 1.0f / (float)NN;
    float mu = bn_stats[tid] * inv_n;
    float var = bn_stats[128 + tid] * inv_n - mu * mu;
    float sc = gamma[tid] * rsqrtf(var + 1e-5f);
    scS[tid] = sc;
    shS[tid] = beta[tid] - mu * sc;
  }
  if (STATS && tid < NCOLS) {
    sS[tid] = 0.f;
    s2S[tid] = 0.f;
  }
  __syncthreads();

  const int wv = tid >> 6;
  const int lane = tid & 63;
  const int l16 = lane & 15;
  const int quad = lane >> 4;
  const int arow = blockIdx.x * 64 + wv * 16 + l16;  // A row (m = lane&15)
  const bool rv = arow < NN;

  // ----- build the 4 per-kc A fragments -----
  V8 afs[4];
  if (AMODE == 3) {
    float ac[4][8];
#pragma unroll
    for (int kc = 0; kc < 4; ++kc) {
      V8 w;
      w.u4 = rv ? *(const uint4*)(Aptr + (size_t)arow * DD + kc * 32 + quad * 8)
                : make_uint4(0u, 0u, 0u, 0u);
#pragma unroll
      for (int j = 0; j < 8; ++j) ac[kc][j] = b2f(w.us[j]);
    }
    if (rv) {
      const size_t base = (size_t)arow * CAP;
      const int c = cnt[arow];
      int p = 0;
      for (; p + 2 <= c; p += 2) {
        const int s0 = csr[base + p], s1 = csr[base + p + 1];
        V8 w0[4], w1[4];
#pragma unroll
        for (int kc = 0; kc < 4; ++kc) {
          w0[kc].u4 = *(const uint4*)(Aptr + (size_t)s0 * DD + kc * 32 + quad * 8);
          w1[kc].u4 = *(const uint4*)(Aptr + (size_t)s1 * DD + kc * 32 + quad * 8);
        }
#pragma unroll
        for (int kc = 0; kc < 4; ++kc)
#pragma unroll
          for (int j = 0; j < 8; ++j)
            ac[kc][j] += b2f(w0[kc].us[j]) + b2f(w1[kc].us[j]);
      }
      if (p < c) {
        const int s0 = csr[base + p];
        V8 w0[4];
#pragma unroll
        for (int kc = 0; kc < 4; ++kc)
          w0[kc].u4 = *(const uint4*)(Aptr + (size_t)s0 * DD + kc * 32 + quad * 8);
#pragma unroll
        for (int kc = 0; kc < 4; ++kc)
#pragma unroll
          for (int j = 0; j < 8; ++j) ac[kc][j] += b2f(w0[kc].us[j]);
      }
    }
#pragma unroll
    for (int kc = 0; kc < 4; ++kc)
#pragma unroll
      for (int j = 0; j < 8; ++j) afs[kc].us[j] = f2b(ac[kc][j]);
  } else {
#pragma unroll
    for (int kc = 0; kc < 4; ++kc) {
      const int k0 = kc * 32 + quad * 8;
      afs[kc].u4 = rv ? *(const uint4*)(Aptr + (size_t)arow * DD + k0)
                      : make_uint4(0u, 0u, 0u, 0u);
      if (AMODE == 2) {
#pragma unroll
        for (int j = 0; j < 8; ++j) {
          float f = fmaf(b2f(afs[kc].us[j]), scS[k0 + j], shS[k0 + j]);
          afs[kc].us[j] = f2b(fmaxf(f, 0.0f));
        }
      }
    }
  }

  // ----- MFMA -----
  f32x4 acc[NCOLS / 16];
#pragma unroll
  for (int nt = 0; nt < NCOLS / 16; ++nt) acc[nt] = (f32x4)(0.0f);
#pragma unroll
  for (int kc = 0; kc < 4; ++kc) {
    const int k0 = kc * 32 + quad * 8;
#pragma unroll
    for (int nt = 0; nt < NCOLS / 16; ++nt) {
      V8 bf;
      bf.u4 = *(const uint4*)&bT[nt * 16 + l16][k0];
      acc[nt] = __builtin_amdgcn_mfma_f32_16x16x32_bf16(afs[kc].s8, bf.s8, acc[nt], 0, 0, 0);
    }
  }

  // C/D layout: col = lane&15, row = quad*4 + reg
  const int r0 = blockIdx.x * 64 + wv * 16 + quad * 4;
#pragma unroll
  for (int nt = 0; nt < NCOLS / 16; ++nt) {
    const int col = nt * 16 + l16;
    const float bv = biasS[col];
    float s = 0.f, s2 = 0.f;
#pragma unroll
    for (int i = 0; i < 4; ++i) {
      const int r = r0 + i;
      if (r < NN) {
        float v = acc[nt][i] + bv;
        if (EPI == 1) v = fmaxf(v, 0.0f);
        if (EPI == 2) {
          ((float*)Cptr)[(size_t)r * NCOLS + col] = v;
        } else {
          unsigned short us = f2b(v);
          ((unsigned short*)Cptr)[(size_t)r * NCOLS + col] = us;
          if (STATS) {
            float vr = b2f(us);  // stats on rounded value (matches gemm2's input)
            s += vr;
            s2 += vr * vr;
          }
        }
      }
    }
    if (STATS) {
      s += __shfl_xor(s, 16);
      s += __shfl_xor(s, 32);
      s2 += __shfl_xor(s2, 16);
      s2 += __shfl_xor(s2, 32);
      if (quad == 0) {
        atomicAdd(&sS[col], s);
        atomicAdd(&s2S[col], s2);
      }
    }
  }
  if (STATS) {
    __syncthreads();
    if (tid < NCOLS) {
      atomicAdd(&stats_out[tid], sS[tid]);
      atomicAdd(&stats_out[128 + tid], s2S[tid]);
    }
  }
}

// ---------- launch ----------
extern "C" void kernel_launch(void* const* d_in, const int* in_sizes, int n_in,
                              void* d_out, int out_size, void* d_ws, size_t ws_size,
                              hipStream_t stream) {
  const float* x = (const float*)d_in[0];
  const int* ei = (const int*)d_in[1];
  const float* W1 = (const float*)d_in[2];
  const float* b1 = (const float*)d_in[3];
  const float* g1 = (const float*)d_in[4];
  const float* be1 = (const float*)d_in[5];
  const float* W2 = (const float*)d_in[6];
  const float* b2 = (const float*)d_in[7];
  const float* fW1 = (const float*)d_in[8];
  const float* fb1 = (const float*)d_in[9];
  const float* fg1 = (const float*)d_in[10];
  const float* fbe1 = (const float*)d_in[11];
  const float* fW2 = (const float*)d_in[12];
  const float* fb2 = (const float*)d_in[13];

  char* ws = (char*)d_ws;
  unsigned short* x16 = (unsigned short*)ws;                       // 25.6 MB
  unsigned short* t16 = (unsigned short*)(ws + (size_t)25600000);  // 25.6 MB
  int* packed = (int*)t16;  // 12.8 MB, consumed by scatter before t16 is written
  int* csr = (int*)(ws + (size_t)51200000);         // NN*CAP*4 = 25.6 MB
  int* cnt = (int*)(ws + (size_t)76800000);         // 400 KB
  float* stats4 = (float*)(ws + (size_t)77200000);  // 4 x 256 f
  int* flag = (int*)(ws + (size_t)77204992);
  unsigned short* wt = (unsigned short*)(ws + (size_t)77210000);  // 256 KB

  const int vecBlocks = (NN * DD) / (256 * 8);  // 6250
  const int gemmBlocks = (NN + 63) / 64;        // 1563
  const int edgeBlocks = NE / 256;              // 6250
  const int filtBlocks = NGROUP * 8;            // 2048

  detect_k<<<1, 64, 0, stream>>>(ei, flag);
  (void)hipMemsetAsync(stats4, 0, 4 * 256 * sizeof(float), stream);
  cast_k<<<vecBlocks, 256, 0, stream>>>(x, x16);
  pack_k<<<edgeBlocks, 256, 0, stream>>>(ei, packed, cnt, flag);
  wprep_k<<<480, 256, 0, stream>>>(W1, W2, fW1, fW2, wt);
  scatter_k<<<filtBlocks, 256, 0, stream>>>((const long long*)packed, cnt, csr);

  for (int l = 0; l < 3; ++l) {
    gemm_k<3, 128, 0, 1><<<gemmBlocks, 256, 0, stream>>>(
        x16, wt + (size_t)l * 16384, b1 + l * 128, nullptr, nullptr, nullptr, t16,
        stats4 + l * 256, cnt, csr);
    gemm_k<2, 128, 1, 0><<<gemmBlocks, 256, 0, stream>>>(
        t16, wt + (size_t)(3 + l) * 16384, b2 + l * 128, stats4 + l * 256,
        g1 + l * 128, be1 + l * 128, x16, nullptr, nullptr, nullptr);
  }

  // final MLP: Linear -> BN -> ReLU -> Linear, out fp32 [NN x 64]
  gemm_k<1, 128, 0, 1><<<gemmBlocks, 256, 0, stream>>>(
      x16, wt + (size_t)6 * 16384, fb1, nullptr, nullptr, nullptr, t16,
      stats4 + 3 * 256, nullptr, nullptr);
  gemm_k<2, 64, 2, 0><<<gemmBlocks, 256, 0, stream>>>(
      t16, wt + (size_t)7 * 16384, fb2, stats4 + 3 * 256, fg1, fbe1, (float*)d_out,
      nullptr, nullptr, nullptr);
}